// Round 7
// baseline (131.464 us; speedup 1.0000x reference)
//
#include <hip/hip_runtime.h>

// CTC loss forward, f64 prob-domain with power-of-2 rescaling.
// v8: v5/v7 skeleton (fwd/bwd separate blocks, 4 waves x 4 states, ghost-
// zone halo, chunked rescale) + FORCED per-chunk register bursts.
// v7 post-mortem: VGPR_Count=84 proved the compiler SANK the 96-float
// column burst back into the step loop (and blank-from-global added L2
// latency per pair) -> null. v8 forces the schedule:
//  (a) column burst (ca, cb gathers + blank broadcast, all LDS) followed by
//      __builtin_amdgcn_sched_barrier(0) -- loads cannot sink past it;
//  (b) DOUBLE-BUFFERED column register sets (S0/S1): burst for chunk k+1
//      issues mid-chunk k (DMA landed a chunk earlier), streaming back
//      under the pure-VALU pair compute;
//  (c) steps run 100% from registers; macros (not pointer-passing lambdas)
//      keep all array indexing compile-time so sets stay in VGPRs;
//  (d) combine folded into fb kernel: last finisher per batch (device-scope
//      atomicAdd on memset-zeroed flag, no spin) does the dot+log.
// f64 op order per state IDENTICAL to v7/v5 -> bit-identical, absmax 0.
// ws layout per b (doubles, stride 1028): [0..512] alphaF, [513] toteF,
// [514..1026] betaB, [1027] toteB; flags (int) at double-offset 64*1028.

#define Bc 64
#define Tc 1024
#define Cc 128
#define Lc 256
#define Sc 513
#define BLANKc 127
#define CHUNK 32
#define NW 4
#define PADS 64
#define WSSTRIDE 1028
#define FLAGS_OFF (Bc * WSSTRIDE)

constexpr float EPSF = 1e-7f;

#define DPPMAXI(x, ctrl) max(x, __builtin_amdgcn_update_dpp( \
    0, x, ctrl, 0xf, 0xf, true))

__device__ __forceinline__ double dpp_wave_shr1_f64(double x) {
    // lane l <- lane l-1; lane 0 <- 0 (bound_ctrl)
    union { double d; int i[2]; } u, r;
    u.d = x;
    r.i[0] = __builtin_amdgcn_update_dpp(0, u.i[0], 0x138, 0xf, 0xf, true);
    r.i[1] = __builtin_amdgcn_update_dpp(0, u.i[1], 0x138, 0xf, 0xf, true);
    return r.d;
}
__device__ __forceinline__ double dpp_wave_shl1_f64(double x) {
    // lane l <- lane l+1; lane 63 <- 0 (bound_ctrl)
    union { double d; int i[2]; } u, r;
    u.d = x;
    r.i[0] = __builtin_amdgcn_update_dpp(0, u.i[0], 0x130, 0xf, 0xf, true);
    r.i[1] = __builtin_amdgcn_update_dpp(0, u.i[1], 0x130, 0xf, 0xf, true);
    return r.d;
}
__device__ __forceinline__ float dpp_wave_shl1_f32(float x) {
    union { float f; int i; } u, r;
    u.f = x;
    r.i = __builtin_amdgcn_update_dpp(0, u.i, 0x130, 0xf, 0xf, true);
    return r.f;
}

// ---- column burst macros (array NAME tokens -> static indexing only) ----
#define BURST_F(Aa, Ca, Ba, rb) do {                                       \
    _Pragma("unroll")                                                      \
    for (int t = 0; t < CHUNK; ++t) {                                      \
        Aa[t] = (rb)[t * Cc + ca];                                         \
        Ca[t] = (rb)[t * Cc + cb];                                         \
        Ba[t] = (rb)[t * Cc + BLANKc];                                     \
    }                                                                      \
    __builtin_amdgcn_sched_barrier(0);                                     \
} while (0)

#define BURST_B(Aa, Ca, Ba, rb) do {                                       \
    _Pragma("unroll")                                                      \
    for (int t = CHUNK - 1; t >= 0; --t) {                                 \
        Aa[t] = (rb)[t * Cc + ca];                                         \
        Ca[t] = (rb)[t * Cc + cb];                                         \
        Ba[t] = (rb)[t * Cc + BLANKc];                                     \
    }                                                                      \
    __builtin_amdgcn_sched_barrier(0);                                     \
} while (0)

#define DOPAIR_F(Aa, Ca, Ba, r) do {                                       \
    Eb = (double)(Ba[r] + EPSF);                                           \
    Ea = (double)(Aa[r] + EPSF);                                           \
    Ec = (double)(Ca[r] + EPSF);                                           \
    stepE();                                                               \
    Ob = (double)(Ba[(r) + 1] + EPSF);                                     \
    Oa = (double)(Aa[(r) + 1] + EPSF);                                     \
    Oc = (double)(Ca[(r) + 1] + EPSF);                                     \
    stepO();                                                               \
} while (0)

#define DOPAIR_B(Aa, Ca, Ba, r) do {                                       \
    Ob = (double)(Ba[(r) + 1] + EPSF);                                     \
    Oa = (double)(Aa[(r) + 1] + EPSF);                                     \
    Oc = (double)(Ca[(r) + 1] + EPSF);                                     \
    Od = (double)(dpp_wave_shl1_f32(Aa[(r) + 1]) + EPSF);                  \
    stepBO();                                                              \
    Eb = (double)(Ba[r] + EPSF);                                           \
    Ea = (double)(Aa[r] + EPSF);                                           \
    Ec = (double)(Ca[r] + EPSF);                                           \
    Ed = (double)(dpp_wave_shl1_f32(Aa[r]) + EPSF);                        \
    stepBE();                                                              \
} while (0)

#define CHUNKF(Aa, Ca, Ba, An, Cn, Bn, nxtbuf, do_burst) do {              \
    _Pragma("unroll")                                                      \
    for (int p = 0; p < 8; ++p) DOPAIR_F(Aa, Ca, Ba, 2 * p);               \
    if (do_burst) BURST_F(An, Cn, Bn, nxtbuf);                             \
    _Pragma("unroll")                                                      \
    for (int p = 8; p < 16; ++p) DOPAIR_F(Aa, Ca, Ba, 2 * p);              \
} while (0)

#define CHUNKB(Aa, Ca, Ba, An, Cn, Bn, nxtbuf, do_burst) do {              \
    _Pragma("unroll")                                                      \
    for (int p = 15; p >= 8; --p) DOPAIR_B(Aa, Ca, Ba, 2 * p);             \
    if (do_burst) BURST_B(An, Cn, Bn, nxtbuf);                             \
    _Pragma("unroll")                                                      \
    for (int p = 7; p >= 0; --p) DOPAIR_B(Aa, Ca, Ba, 2 * p);              \
} while (0)

__global__ __launch_bounds__(256, 1) void ctc_fb_kernel(
    const int* __restrict__ y_true,        // [B, L]
    const float* __restrict__ y_pred,      // [B, T, C]
    const int* __restrict__ label_length,  // [B, 1]
    double* __restrict__ ws,
    float* __restrict__ out)               // [B, 1]
{
    const int bb = blockIdx.x;
    const int b = bb >> 1;
    const bool isF = !(bb & 1);
    const int tid = (int)threadIdx.x;
    const int wl = tid >> 6;               // wave 0..3
    const int lane = tid & 63;

    __shared__ float bufs[3][CHUNK * Cc];  // 3 x 16 KB staged y_pred rows
    __shared__ double ash[Sc];             // owned-alpha/beta exchange
    __shared__ int em[NW];                 // per-wave masked exponent max
    __shared__ int amlast;

    const int lab_len = label_length[b];
    const float* yp = y_pred + (size_t)b * Tc * Cc;
    const int* lab = y_true + b * Lc;
    double* wsb = ws + (size_t)b * WSSTRIDE;

    // ---- region geometry (starts EVEN). fwd pads BELOW owned, bwd ABOVE.
    const int start = isF ? ((wl == 0) ? 0 : (128 * wl - PADS)) : (128 * wl);
    const int own_s = 128 * wl;
    const int own_e = (wl == NW - 1) ? Sc : (128 * (wl + 1));
    const int s0 = start + 4 * lane;       // even; lane holds s0..s0+3

    // ---- per-lane static metadata ----
    const int li0 = s0 >> 1;               // label idx of state s0+1
    const int li0c = min(li0, Lc - 1);
    const int li1c = min(li0 + 1, Lc - 1);
    const int li2c = min(li0 + 2, Lc - 1);
    const int ca = lab[li0c], cb = lab[li1c], cc = lab[li2c];
    const double sm_a = (li0 > 0 && ca != BLANKc && ca != lab[li0c - 1]) ? 1.0 : 0.0;
    const double sm_b = (cb != BLANKc && cb != ca) ? 1.0 : 0.0;
    const double sm_c = (cc != BLANKc && cc != cb) ? 1.0 : 0.0;

    const int S2 = 2 * lab_len + 1;
    const bool ow0 = (s0     >= own_s) && (s0     < own_e);
    const bool ow1 = (s0 + 1 >= own_s) && (s0 + 1 < own_e);
    const bool ow2 = (s0 + 2 >= own_s) && (s0 + 2 < own_e);
    const bool ow3 = (s0 + 3 >= own_s) && (s0 + 3 < own_e);
    const int om0 = (ow0 && s0     < S2) ? -1 : 0;
    const int om1 = (ow1 && s0 + 1 < S2) ? -1 : 0;
    const int om2 = (ow2 && s0 + 2 < S2) ? -1 : 0;
    const int om3 = (ow3 && s0 + 3 < S2) ? -1 : 0;

    // ---- staging: each wave DMAs its quarter (4 KB) of a 16 KB chunk ----
    auto stage = [&](int c, float* dst) {
        const float* g = yp + (size_t)c * (CHUNK * Cc) + lane * 4;
        #pragma unroll
        for (int q = 0; q < 4; ++q) {
            const int i = wl * 4 + q;
            __builtin_amdgcn_global_load_lds(
                (const __attribute__((address_space(1))) void*)(g + i * 256),
                (__attribute__((address_space(3))) void*)(dst + i * 256),
                16, 0, 0);
        }
    };

    // ---- double-buffered column register sets ----
    float A0[CHUNK], C0[CHUNK], B0[CHUNK];
    float A1[CHUNK], C1[CHUNK], B1[CHUNK];

    if (isF) {
        // =================== FORWARD: rows 0 .. 511 ===================
        double a0 = 0, a1 = 0, a2 = 0, a3 = 0, n3 = 0;
        int tote = 0;
        double Eb, Ea, Ec, Ob, Oa, Oc;

        auto stepE = [&]() {
            const double t3 = __fma_rn(sm_b, a1, a3 + a2);
            const double t2 = a2 + a1;
            const double t1 = __fma_rn(sm_a, n3, a1 + a0);
            const double t0 = a0 + n3;
            a3 = t3 * Ec;
            n3 = dpp_wave_shr1_f64(a3);
            a2 = t2 * Eb; a1 = t1 * Ea; a0 = t0 * Eb;
        };
        auto stepO = [&]() {
            const double t3 = __fma_rn(sm_b, a1, a3 + a2);
            const double t2 = a2 + a1;
            const double t1 = __fma_rn(sm_a, n3, a1 + a0);
            const double t0 = a0 + n3;
            a3 = t3 * Oc;
            n3 = dpp_wave_shr1_f64(a3);
            a2 = t2 * Ob; a1 = t1 * Oa; a0 = t0 * Ob;
        };
        auto syncex = [&](int sk) {
            int e =        om0 & (__double2hiint(a0) >> 20);
            e = max(e, om1 & (__double2hiint(a1) >> 20));
            e = max(e, om2 & (__double2hiint(a2) >> 20));
            e = max(e, om3 & (__double2hiint(a3) >> 20));
            e = DPPMAXI(e, 0x111); e = DPPMAXI(e, 0x112);
            e = DPPMAXI(e, 0x114); e = DPPMAXI(e, 0x118);
            e = DPPMAXI(e, 0x142); e = DPPMAXI(e, 0x143);
            if (lane == 63) em[wl] = e;
            if (ow0) ash[s0]     = a0;
            if (ow1) ash[s0 + 1] = a1;
            if (ow2) ash[s0 + 2] = a2;
            if (ow3) ash[s0 + 3] = a3;
            __syncthreads();               // barrier 1
            const int eg = max(max(em[0], em[1]), max(em[2], em[3]));
            const int sexp = min(max(2046 - eg, 1), 2045);
            const double sc = __hiloint2double(sexp << 20, 0);
            tote += 1023 - sexp;
            if (wl > 0 && lane < (PADS / 4)) {   // refresh pad from below-owner
                a0 = ash[s0];     a1 = ash[s0 + 1];
                a2 = ash[s0 + 2]; a3 = ash[s0 + 3];
            }
            a0 *= sc; a1 *= sc; a2 *= sc; a3 *= sc;
            n3 = dpp_wave_shr1_f64(a3);
            __syncthreads();               // barrier 2
            if (sk <= 15) stage(sk, bufs[sk % 3]);  // DMA after barrier
        };

        // ---- prologue ----
        stage(0, bufs[0]); stage(1, bufs[1]); stage(2, bufs[2]);
        __syncthreads();

        // chunk 0 (set S0): init from row 0, lone t=1, pairs 1..15
        BURST_F(A0, C0, B0, bufs[0]);
        if (wl == 0 && lane == 0) {
            a0 = (double)(B0[0] + EPSF);                         // s=0
            if (lab_len > 0) a1 = (double)(A0[0] + EPSF);        // s=1
        }
        Ob = (double)(B0[1] + EPSF);
        Oa = (double)(A0[1] + EPSF);
        Oc = (double)(C0[1] + EPSF);
        stepO();                           // lone step t=1
        #pragma unroll
        for (int p = 1; p < 8; ++p) DOPAIR_F(A0, C0, B0, 2 * p);
        BURST_F(A1, C1, B1, bufs[1]);      // mid-chunk burst for chunk 1
        #pragma unroll
        for (int p = 8; p < 16; ++p) DOPAIR_F(A0, C0, B0, 2 * p);

        // chunks 1..15, alternating sets
        for (int kp = 0; kp < 7; ++kp) {
            const int k1 = 2 * kp + 1;     // odd chunk: uses S1, bursts S0
            syncex(k1 + 2);
            CHUNKF(A1, C1, B1, A0, C0, B0, bufs[(k1 + 1) % 3], true);
            const int k2 = k1 + 1;         // even chunk: uses S0, bursts S1
            syncex(k2 + 2);
            CHUNKF(A0, C0, B0, A1, C1, B1, bufs[(k2 + 1) % 3], true);
        }
        syncex(17);                        // rescale only (sk>15)
        CHUNKF(A1, C1, B1, A1, C1, B1, bufs[0], false);   // chunk 15

        // publish alpha_511 (pre-rescale) + toteF
        if (ow0) wsb[s0]     = a0;
        if (ow1) wsb[s0 + 1] = a1;
        if (ow2) wsb[s0 + 2] = a2;
        if (ow3) wsb[s0 + 3] = a3;
        if (tid == 0) wsb[513] = (double)tote;
    } else {
        // =================== BACKWARD: rows 1023 .. 512 ===================
        double b0 = 0, b1 = 0, b2 = 0, b3 = 0, n0 = 0, n1 = 0;
        int tote = 0;
        double Eb, Ea, Ec, Ed, Ob, Oa, Oc, Od;

        auto stepBE = [&]() {
            const double x1 = Ea * b1, x2 = Eb * b2, x3 = Ec * b3, z = Ed * n1;
            const double r0 = __fma_rn(Eb, b0, x1);
            const double r1 = __fma_rn(sm_b, x3, x1 + x2);
            const double r2 = x2 + x3;
            const double r3 = __fma_rn(sm_c, z, __fma_rn(Eb, n0, x3));
            b0 = r0; b1 = r1; b2 = r2; b3 = r3;
            n0 = dpp_wave_shl1_f64(b0);
            n1 = dpp_wave_shl1_f64(b1);
        };
        auto stepBO = [&]() {
            const double x1 = Oa * b1, x2 = Ob * b2, x3 = Oc * b3, z = Od * n1;
            const double r0 = __fma_rn(Ob, b0, x1);
            const double r1 = __fma_rn(sm_b, x3, x1 + x2);
            const double r2 = x2 + x3;
            const double r3 = __fma_rn(sm_c, z, __fma_rn(Ob, n0, x3));
            b0 = r0; b1 = r1; b2 = r2; b3 = r3;
            n0 = dpp_wave_shl1_f64(b0);
            n1 = dpp_wave_shl1_f64(b1);
        };
        auto syncex = [&](int sk) {
            int e =        om0 & (__double2hiint(b0) >> 20);
            e = max(e, om1 & (__double2hiint(b1) >> 20));
            e = max(e, om2 & (__double2hiint(b2) >> 20));
            e = max(e, om3 & (__double2hiint(b3) >> 20));
            e = DPPMAXI(e, 0x111); e = DPPMAXI(e, 0x112);
            e = DPPMAXI(e, 0x114); e = DPPMAXI(e, 0x118);
            e = DPPMAXI(e, 0x142); e = DPPMAXI(e, 0x143);
            if (lane == 63) em[wl] = e;
            if (ow0) ash[s0]     = b0;
            if (ow1) ash[s0 + 1] = b1;
            if (ow2) ash[s0 + 2] = b2;
            if (ow3) ash[s0 + 3] = b3;
            __syncthreads();               // barrier 1
            const int eg = max(max(em[0], em[1]), max(em[2], em[3]));
            const int sexp = min(max(2046 - eg, 1), 2045);
            const double sc = __hiloint2double(sexp << 20, 0);
            tote += 1023 - sexp;
            // refresh pad above from owner; zero beyond S space
            if (s0     >= own_e) b0 = (s0     < Sc) ? ash[s0]     : 0.0;
            if (s0 + 1 >= own_e) b1 = (s0 + 1 < Sc) ? ash[s0 + 1] : 0.0;
            if (s0 + 2 >= own_e) b2 = (s0 + 2 < Sc) ? ash[s0 + 2] : 0.0;
            if (s0 + 3 >= own_e) b3 = (s0 + 3 < Sc) ? ash[s0 + 3] : 0.0;
            b0 *= sc; b1 *= sc; b2 *= sc; b3 *= sc;
            n0 = dpp_wave_shl1_f64(b0);
            n1 = dpp_wave_shl1_f64(b1);
            __syncthreads();               // barrier 2
            if (sk >= 16) stage(sk, bufs[(31 - sk) % 3]);
        };

        // ---- prologue: chunks 31,30,29 -> bufs 0,1,2 ----
        stage(31, bufs[0]); stage(30, bufs[1]); stage(29, bufs[2]);
        __syncthreads();

        // init beta_{1023}: 1 at end states {2L, 2L-1}
        {
            const int e0 = 2 * lab_len;
            const int e1 = (lab_len > 0) ? (2 * lab_len - 1) : e0;
            b0 = (s0     == e0 || s0     == e1) ? 1.0 : 0.0;
            b1 = (s0 + 1 == e0 || s0 + 1 == e1) ? 1.0 : 0.0;
            b2 = (s0 + 2 == e0 || s0 + 2 == e1) ? 1.0 : 0.0;
            b3 = (s0 + 3 == e0 || s0 + 3 == e1) ? 1.0 : 0.0;
            n0 = dpp_wave_shl1_f64(b0);
            n1 = dpp_wave_shl1_f64(b1);
        }
        // chunk 31 (set S0): pairs 15..8, mid-burst S1(chunk 30), pairs 7..0
        BURST_B(A0, C0, B0, bufs[0]);
        #pragma unroll
        for (int p = 15; p >= 8; --p) DOPAIR_B(A0, C0, B0, 2 * p);
        BURST_B(A1, C1, B1, bufs[1]);
        #pragma unroll
        for (int p = 7; p >= 0; --p) DOPAIR_B(A0, C0, B0, 2 * p);

        // chunks 30..16, alternating sets
        for (int kp = 0; kp < 7; ++kp) {
            const int c1 = 30 - 2 * kp;    // uses S1, bursts S0(c1-1)
            syncex(c1 - 2);
            CHUNKB(A1, C1, B1, A0, C0, B0, bufs[(32 - c1) % 3], true);
            const int c2 = c1 - 1;         // uses S0, bursts S1(c2-1)
            syncex(c2 - 2);
            CHUNKB(A0, C0, B0, A1, C1, B1, bufs[(32 - c2) % 3], true);
        }
        syncex(14);                        // rescale only (sk<16)
        CHUNKB(A1, C1, B1, A1, C1, B1, bufs[0], false);   // chunk 16

        // publish beta_511 (pre-rescale) + toteB
        if (ow0) wsb[514 + s0]     = b0;
        if (ow1) wsb[514 + s0 + 1] = b1;
        if (ow2) wsb[514 + s0 + 2] = b2;
        if (ow3) wsb[514 + s0 + 3] = b3;
        if (tid == 0) wsb[1027] = (double)tote;
    }

    // ---- folded combine: last finisher for batch b does dot + log ----
    __threadfence();                       // release our ws writes
    if (tid == 0) {
        int* flags = (int*)(ws + FLAGS_OFF);
        amlast = (atomicAdd(&flags[b], 1) == 1);
    }
    __syncthreads();
    if (amlast && tid < 64) {
        __threadfence();                   // acquire other block's writes
        const double* wf = ws + (size_t)b * WSSTRIDE;
        const double* wb = wf + 514;
        int eP = 0;                        // max biased-exponent product sum
        for (int s = tid; s < S2; s += 64) {
            const int ea = (__double2hiint(wf[s]) >> 20) & 0x7ff;
            const int eb2 = (__double2hiint(wb[s]) >> 20) & 0x7ff;
            if (ea && eb2) eP = max(eP, ea + eb2);
        }
        #pragma unroll
        for (int m = 1; m < 64; m <<= 1) eP = max(eP, __shfl_xor(eP, m));
        const int sh = 2046 - eP;
        int k1 = sh / 2;
        int k2 = sh - k1;
        k1 = min(max(k1, -1022), 1023);
        k2 = min(max(k2, -1022), 1023);
        const double scA = __hiloint2double((1023 + k1) << 20, 0);
        const double scB = __hiloint2double((1023 + k2) << 20, 0);
        double dot = 0.0;
        for (int s = tid; s < S2; s += 64)
            dot += (wf[s] * scA) * (wb[s] * scB);
        #pragma unroll
        for (int m = 1; m < 64; m <<= 1) dot += __shfl_xor(dot, m);
        if (tid == 0) {
            const double lt = wf[513] + wb[513] - (double)k1 - (double)k2;
            out[b] = (float)(-(log(dot) + lt * 0.6931471805599453));
        }
    }
}

extern "C" void kernel_launch(void* const* d_in, const int* in_sizes, int n_in,
                              void* d_out, int out_size, void* d_ws, size_t ws_size,
                              hipStream_t stream) {
    const int*   y_true       = (const int*)d_in[0];
    const float* y_pred       = (const float*)d_in[1];
    const int*   label_length = (const int*)d_in[3];
    float* out = (float*)d_out;
    double* ws = (double*)d_ws;

    hipMemsetAsync((char*)d_ws + FLAGS_OFF * sizeof(double), 0,
                   Bc * sizeof(int), stream);
    ctc_fb_kernel<<<2 * Bc, NW * 64, 0, stream>>>(y_true, y_pred,
                                                  label_length, ws, out);
}

// Round 8
// 121.431 us; speedup vs baseline: 1.0826x; 1.0826x over previous
//
#include <hip/hip_runtime.h>

// CTC loss forward, f64 prob-domain with power-of-2 rescaling.
// v9: v5 skeleton (fwd/bwd separate blocks, 4 waves x 4 states, ghost-zone
// halo, chunked rescale, 2-kernel) + LDS-pipe relief + DEEP slot pipeline.
// v8 post-mortem: WRITE_SIZE 516->1125KB = column arrays spilled to scratch;
// forced register buffers fail (compiler sinks or spills). v5 budget was
// ADDITIVE: VALU ~73 cy/step + LDS ~106 cy/step (3-pair lookahead ~420 cy <
// 4-way-shared LDS queue ~700 cy -> lgkm waits exposed every pair).
// v9 keeps v5's proven rotating-slot structure and changes only delivery:
//  (a) blank column from GLOBAL inside the slots (uniform addr, 1 line,
//      L2-hot from staging DMA, vmcnt pipe) -- removes ~128 LDS instr/chunk
//      (~36 cy/step off the contended LDS pipe);
//  (b) slot pipeline depth 3 -> 6 pairs (sl[8][6]): pair P gathered at
//      iter P-6, consumed at P-1 -> ~900 cy cover > queue+latency;
//  (c) bwd cc column derived via f32 DPP of neighbor's ca at expand
//      (lane-63 garbage multiplies n1=0) -- 2 fewer gathers/pair.
// All consumed f32 bits identical to v5 -> bit-identical f64 -> absmax 0.
// ws layout per b (doubles, stride 1028): [0..512] alphaF, [513] toteF,
// [514..1026] betaB, [1027] toteB.

#define Bc 64
#define Tc 1024
#define Cc 128
#define Lc 256
#define Sc 513
#define BLANKc 127
#define CHUNK 32
#define NW 4
#define PADS 64
#define WSSTRIDE 1028

constexpr float EPSF = 1e-7f;

#define DPPMAXI(x, ctrl) max(x, __builtin_amdgcn_update_dpp( \
    0, x, ctrl, 0xf, 0xf, true))

__device__ __forceinline__ double dpp_wave_shr1_f64(double x) {
    // lane l <- lane l-1; lane 0 <- 0 (bound_ctrl)
    union { double d; int i[2]; } u, r;
    u.d = x;
    r.i[0] = __builtin_amdgcn_update_dpp(0, u.i[0], 0x138, 0xf, 0xf, true);
    r.i[1] = __builtin_amdgcn_update_dpp(0, u.i[1], 0x138, 0xf, 0xf, true);
    return r.d;
}
__device__ __forceinline__ double dpp_wave_shl1_f64(double x) {
    // lane l <- lane l+1; lane 63 <- 0 (bound_ctrl)
    union { double d; int i[2]; } u, r;
    u.d = x;
    r.i[0] = __builtin_amdgcn_update_dpp(0, u.i[0], 0x130, 0xf, 0xf, true);
    r.i[1] = __builtin_amdgcn_update_dpp(0, u.i[1], 0x130, 0xf, 0xf, true);
    return r.d;
}
__device__ __forceinline__ float dpp_wave_shl1_f32(float x) {
    union { float f; int i; } u, r;
    u.f = x;
    r.i = __builtin_amdgcn_update_dpp(0, u.i, 0x130, 0xf, 0xf, true);
    return r.f;
}

__global__ __launch_bounds__(256, 1) void ctc_fb_kernel(
    const int* __restrict__ y_true,        // [B, L]
    const float* __restrict__ y_pred,      // [B, T, C]
    const int* __restrict__ label_length,  // [B, 1]
    double* __restrict__ ws)
{
    const int bb = blockIdx.x;
    const int b = bb >> 1;
    const bool isF = !(bb & 1);
    const int tid = (int)threadIdx.x;
    const int wl = tid >> 6;               // wave 0..3
    const int lane = tid & 63;

    __shared__ float bufs[3][CHUNK * Cc];  // 3 x 16 KB staged y_pred rows
    __shared__ double ash[Sc];             // owned-alpha/beta exchange
    __shared__ int em[NW];                 // per-wave masked exponent max

    const int lab_len = label_length[b];
    const float* yp = y_pred + (size_t)b * Tc * Cc;
    const int* lab = y_true + b * Lc;
    double* wsb = ws + (size_t)b * WSSTRIDE;

    // ---- region geometry (starts EVEN). fwd pads BELOW owned, bwd ABOVE.
    const int start = isF ? ((wl == 0) ? 0 : (128 * wl - PADS)) : (128 * wl);
    const int own_s = 128 * wl;
    const int own_e = (wl == NW - 1) ? Sc : (128 * (wl + 1));
    const int s0 = start + 4 * lane;       // even; lane holds s0..s0+3

    // ---- per-lane static metadata ----
    const int li0 = s0 >> 1;               // label idx of state s0+1
    const int li0c = min(li0, Lc - 1);
    const int li1c = min(li0 + 1, Lc - 1);
    const int li2c = min(li0 + 2, Lc - 1);
    const int ca = lab[li0c], cb = lab[li1c], cc = lab[li2c];
    const double sm_a = (li0 > 0 && ca != BLANKc && ca != lab[li0c - 1]) ? 1.0 : 0.0;
    const double sm_b = (cb != BLANKc && cb != ca) ? 1.0 : 0.0;
    const double sm_c = (cc != BLANKc && cc != cb) ? 1.0 : 0.0;

    const int S2 = 2 * lab_len + 1;
    const bool ow0 = (s0     >= own_s) && (s0     < own_e);
    const bool ow1 = (s0 + 1 >= own_s) && (s0 + 1 < own_e);
    const bool ow2 = (s0 + 2 >= own_s) && (s0 + 2 < own_e);
    const bool ow3 = (s0 + 3 >= own_s) && (s0 + 3 < own_e);
    const int om0 = (ow0 && s0     < S2) ? -1 : 0;
    const int om1 = (ow1 && s0 + 1 < S2) ? -1 : 0;
    const int om2 = (ow2 && s0 + 2 < S2) ? -1 : 0;
    const int om3 = (ow3 && s0 + 3 < S2) ? -1 : 0;

    // ---- staging: each wave DMAs its quarter (4 KB) of a 16 KB chunk ----
    auto stage = [&](int c, float* dst) {
        const float* g = yp + (size_t)c * (CHUNK * Cc) + lane * 4;
        #pragma unroll
        for (int q = 0; q < 4; ++q) {
            const int i = wl * 4 + q;
            __builtin_amdgcn_global_load_lds(
                (const __attribute__((address_space(1))) void*)(g + i * 256),
                (__attribute__((address_space(3))) void*)(dst + i * 256),
                16, 0, 0);
        }
    };

    // ---- 8 rotating pair slots; pair P lives in sl[P & 7] ----
    // gathered at iter P-6, consumed at iter P-1.
    // layout: [0]=blank_even(G) [1]=blank_odd(G) [2]=ca_e [3]=ca_o
    //         [4]=cb_e [5]=cb_o
    float sl[8][6];

    auto gpair = [&](const float* rowp, const float* growp, float* s) {
        s[0] = growp[0];                   // blank, even row (GLOBAL)
        s[1] = growp[Cc];                  // blank, odd row  (GLOBAL)
        s[2] = rowp[ca]; s[3] = rowp[ca + Cc];
        s[4] = rowp[cb]; s[5] = rowp[cb + Cc];
    };

    if (isF) {
        // =================== FORWARD: rows 0 .. 511 ===================
        double a0 = 0, a1 = 0, a2 = 0, a3 = 0, n3 = 0;
        int tote = 0;
        double Eb, Ea, Ec, Ob, Oa, Oc;

        auto expandE = [&](const float* s) {
            Eb = (double)(s[0] + EPSF); Ea = (double)(s[2] + EPSF);
            Ec = (double)(s[4] + EPSF);
        };
        auto expandO = [&](const float* s) {
            Ob = (double)(s[1] + EPSF); Oa = (double)(s[3] + EPSF);
            Oc = (double)(s[5] + EPSF);
        };
        auto stepE = [&]() {
            const double t3 = __fma_rn(sm_b, a1, a3 + a2);
            const double t2 = a2 + a1;
            const double t1 = __fma_rn(sm_a, n3, a1 + a0);
            const double t0 = a0 + n3;
            a3 = t3 * Ec;
            n3 = dpp_wave_shr1_f64(a3);
            a2 = t2 * Eb; a1 = t1 * Ea; a0 = t0 * Eb;
        };
        auto stepO = [&]() {
            const double t3 = __fma_rn(sm_b, a1, a3 + a2);
            const double t2 = a2 + a1;
            const double t1 = __fma_rn(sm_a, n3, a1 + a0);
            const double t0 = a0 + n3;
            a3 = t3 * Oc;
            n3 = dpp_wave_shr1_f64(a3);
            a2 = t2 * Ob; a1 = t1 * Oa; a0 = t0 * Ob;
        };
        auto syncex = [&](int sk) {
            int e =        om0 & (__double2hiint(a0) >> 20);
            e = max(e, om1 & (__double2hiint(a1) >> 20));
            e = max(e, om2 & (__double2hiint(a2) >> 20));
            e = max(e, om3 & (__double2hiint(a3) >> 20));
            e = DPPMAXI(e, 0x111); e = DPPMAXI(e, 0x112);
            e = DPPMAXI(e, 0x114); e = DPPMAXI(e, 0x118);
            e = DPPMAXI(e, 0x142); e = DPPMAXI(e, 0x143);
            if (lane == 63) em[wl] = e;
            if (ow0) ash[s0]     = a0;
            if (ow1) ash[s0 + 1] = a1;
            if (ow2) ash[s0 + 2] = a2;
            if (ow3) ash[s0 + 3] = a3;
            __syncthreads();               // barrier 1
            const int eg = max(max(em[0], em[1]), max(em[2], em[3]));
            const int sexp = min(max(2046 - eg, 1), 2045);
            const double sc = __hiloint2double(sexp << 20, 0);
            tote += 1023 - sexp;
            if (wl > 0 && lane < (PADS / 4)) {   // refresh pad from below-owner
                a0 = ash[s0];     a1 = ash[s0 + 1];
                a2 = ash[s0 + 2]; a3 = ash[s0 + 3];
            }
            a0 *= sc; a1 *= sc; a2 *= sc; a3 *= sc;
            n3 = dpp_wave_shr1_f64(a3);
            __syncthreads();               // barrier 2
            if (sk <= 15) stage(sk, bufs[sk % 3]);  // DMA after barrier
        };

        // ---- prologue ----
        stage(0, bufs[0]); stage(1, bufs[1]); stage(2, bufs[2]);
        __syncthreads();

        if (wl == 0 && lane == 0) {
            a0 = (double)(bufs[0][BLANKc] + EPSF);               // s=0
            if (lab_len > 0) a1 = (double)(bufs[0][ca] + EPSF);  // s=1
        }
        // prime pairs 1..6 -> sl[1..6]
        #pragma unroll
        for (int pp = 1; pp <= 6; ++pp)
            gpair(bufs[0] + 2 * pp * Cc,
                  yp + (size_t)(2 * pp) * Cc + BLANKc, sl[pp]);
        {
            const float* r1 = bufs[0] + 1 * Cc;
            Ob = (double)(r1[BLANKc] + EPSF);
            Oa = (double)(r1[ca] + EPSF);
            Oc = (double)(r1[cb] + EPSF);
        }
        expandE(sl[1]);                    // row 2

        stepO();                           // lone step t=1
        expandO(sl[1]);                    // row 3

        // chunk 0: pairs 1..15 (rows 2..31)
        {
            const float* rb  = bufs[0];
            const float* rbn = bufs[1];
            const float* gB  = yp + BLANKc;
            #pragma unroll
            for (int qi = 1; qi < 16; ++qi) {
                const int ra = 2 * qi + 12;          // rows of pair qi+6
                const float* nxt = (ra < CHUNK) ? (rb + ra * Cc)
                                                : (rbn + (ra - CHUNK) * Cc);
                gpair(nxt, gB + (size_t)ra * Cc, sl[(qi + 6) & 7]);
                stepE();
                expandE(sl[(qi + 1) & 7]);
                stepO();
                expandO(sl[(qi + 1) & 7]);
            }
        }
        // chunks 1..15 (rows 32..511)
        for (int k = 1; k < 16; ++k) {
            syncex(k + 2);
            const float* rb  = bufs[k % 3];
            const float* rbn = bufs[(k + 1) % 3];    // k=15: dead reads, safe
            const float* gB  = yp + (size_t)k * (CHUNK * Cc) + BLANKc;
            #pragma unroll
            for (int qi = 0; qi < 16; ++qi) {
                const int ra = 2 * qi + 12;
                const float* nxt = (ra < CHUNK) ? (rb + ra * Cc)
                                                : (rbn + (ra - CHUNK) * Cc);
                gpair(nxt, gB + (size_t)ra * Cc, sl[(qi + 6) & 7]);
                stepE();
                expandE(sl[(qi + 1) & 7]);
                stepO();
                expandO(sl[(qi + 1) & 7]);
            }
        }
        // publish alpha_511 (pre-rescale) + toteF
        if (ow0) wsb[s0]     = a0;
        if (ow1) wsb[s0 + 1] = a1;
        if (ow2) wsb[s0 + 2] = a2;
        if (ow3) wsb[s0 + 3] = a3;
        if (tid == 0) wsb[513] = (double)tote;
    } else {
        // =================== BACKWARD: rows 1023 .. 512 ===================
        double b0 = 0, b1 = 0, b2 = 0, b3 = 0, n0 = 0, n1 = 0;
        int tote = 0;
        double Eb, Ea, Ec, Ed, Ob, Oa, Oc, Od;

        auto expandEB = [&](const float* s) {
            Eb = (double)(s[0] + EPSF); Ea = (double)(s[2] + EPSF);
            Ec = (double)(s[4] + EPSF);
            Ed = (double)(dpp_wave_shl1_f32(s[2]) + EPSF);   // cc = nbr ca
        };
        auto expandOB = [&](const float* s) {
            Ob = (double)(s[1] + EPSF); Oa = (double)(s[3] + EPSF);
            Oc = (double)(s[5] + EPSF);
            Od = (double)(dpp_wave_shl1_f32(s[3]) + EPSF);
        };
        auto stepBE = [&]() {
            const double x1 = Ea * b1, x2 = Eb * b2, x3 = Ec * b3, z = Ed * n1;
            const double r0 = __fma_rn(Eb, b0, x1);
            const double r1 = __fma_rn(sm_b, x3, x1 + x2);
            const double r2 = x2 + x3;
            const double r3 = __fma_rn(sm_c, z, __fma_rn(Eb, n0, x3));
            b0 = r0; b1 = r1; b2 = r2; b3 = r3;
            n0 = dpp_wave_shl1_f64(b0);
            n1 = dpp_wave_shl1_f64(b1);
        };
        auto stepBO = [&]() {
            const double x1 = Oa * b1, x2 = Ob * b2, x3 = Oc * b3, z = Od * n1;
            const double r0 = __fma_rn(Ob, b0, x1);
            const double r1 = __fma_rn(sm_b, x3, x1 + x2);
            const double r2 = x2 + x3;
            const double r3 = __fma_rn(sm_c, z, __fma_rn(Ob, n0, x3));
            b0 = r0; b1 = r1; b2 = r2; b3 = r3;
            n0 = dpp_wave_shl1_f64(b0);
            n1 = dpp_wave_shl1_f64(b1);
        };
        auto syncex = [&](int sk) {
            int e =        om0 & (__double2hiint(b0) >> 20);
            e = max(e, om1 & (__double2hiint(b1) >> 20));
            e = max(e, om2 & (__double2hiint(b2) >> 20));
            e = max(e, om3 & (__double2hiint(b3) >> 20));
            e = DPPMAXI(e, 0x111); e = DPPMAXI(e, 0x112);
            e = DPPMAXI(e, 0x114); e = DPPMAXI(e, 0x118);
            e = DPPMAXI(e, 0x142); e = DPPMAXI(e, 0x143);
            if (lane == 63) em[wl] = e;
            if (ow0) ash[s0]     = b0;
            if (ow1) ash[s0 + 1] = b1;
            if (ow2) ash[s0 + 2] = b2;
            if (ow3) ash[s0 + 3] = b3;
            __syncthreads();               // barrier 1
            const int eg = max(max(em[0], em[1]), max(em[2], em[3]));
            const int sexp = min(max(2046 - eg, 1), 2045);
            const double sc = __hiloint2double(sexp << 20, 0);
            tote += 1023 - sexp;
            // refresh pad above from owner; zero beyond S space
            if (s0     >= own_e) b0 = (s0     < Sc) ? ash[s0]     : 0.0;
            if (s0 + 1 >= own_e) b1 = (s0 + 1 < Sc) ? ash[s0 + 1] : 0.0;
            if (s0 + 2 >= own_e) b2 = (s0 + 2 < Sc) ? ash[s0 + 2] : 0.0;
            if (s0 + 3 >= own_e) b3 = (s0 + 3 < Sc) ? ash[s0 + 3] : 0.0;
            b0 *= sc; b1 *= sc; b2 *= sc; b3 *= sc;
            n0 = dpp_wave_shl1_f64(b0);
            n1 = dpp_wave_shl1_f64(b1);
            __syncthreads();               // barrier 2
            if (sk >= 16) stage(sk, bufs[(31 - sk) % 3]);
        };

        // ---- prologue: chunks 31,30,29 -> bufs 0,1,2 ----
        stage(31, bufs[0]); stage(30, bufs[1]); stage(29, bufs[2]);
        __syncthreads();

        // init beta_{1023}: 1 at end states {2L, 2L-1}
        {
            const int e0 = 2 * lab_len;
            const int e1 = (lab_len > 0) ? (2 * lab_len - 1) : e0;
            b0 = (s0     == e0 || s0     == e1) ? 1.0 : 0.0;
            b1 = (s0 + 1 == e0 || s0 + 1 == e1) ? 1.0 : 0.0;
            b2 = (s0 + 2 == e0 || s0 + 2 == e1) ? 1.0 : 0.0;
            b3 = (s0 + 3 == e0 || s0 + 3 == e1) ? 1.0 : 0.0;
            n0 = dpp_wave_shl1_f64(b0);
            n1 = dpp_wave_shl1_f64(b1);
        }
        // prime pairs 15..10 -> sl[7..2]
        #pragma unroll
        for (int pp = 0; pp < 6; ++pp) {
            const int pr = 15 - pp;
            gpair(bufs[0] + 2 * pr * Cc,
                  yp + (size_t)(31 * CHUNK + 2 * pr) * Cc + BLANKc,
                  sl[pr & 7]);
        }
        expandOB(sl[7]);                   // row 31 (abs t=1023)
        expandEB(sl[7]);                   // row 30

        // chunk 31: q = 15..0 (rows descend; odd step first per pair)
        {
            const float* rb  = bufs[0];
            const float* rbn = bufs[1];    // chunk 30
            const float* gB  = yp + (size_t)(31 * CHUNK) * Cc + BLANKc;
            #pragma unroll
            for (int j = 0; j < 16; ++j) {
                const int q = 15 - j;
                const int ra = 2 * q - 12;           // rows of pair q-6
                const float* nxt = (ra >= 0) ? (rb + ra * Cc)
                                             : (rbn + (ra + CHUNK) * Cc);
                gpair(nxt, gB + (ptrdiff_t)ra * Cc, sl[(q + 2) & 7]);
                stepBO();
                expandOB(sl[(q - 1) & 7]);
                stepBE();
                expandEB(sl[(q - 1) & 7]);
            }
        }
        // chunks 30..16
        for (int c = 30; c >= 16; --c) {
            syncex(c - 2);
            const float* rb  = bufs[(31 - c) % 3];
            const float* rbn = bufs[(32 - c) % 3];   // c=16: dead reads, safe
            const float* gB  = yp + (size_t)c * (CHUNK * Cc) + BLANKc;
            #pragma unroll
            for (int j = 0; j < 16; ++j) {
                const int q = 15 - j;
                const int ra = 2 * q - 12;
                const float* nxt = (ra >= 0) ? (rb + ra * Cc)
                                             : (rbn + (ra + CHUNK) * Cc);
                gpair(nxt, gB + (ptrdiff_t)ra * Cc, sl[(q + 2) & 7]);
                stepBO();
                expandOB(sl[(q - 1) & 7]);
                stepBE();
                expandEB(sl[(q - 1) & 7]);
            }
        }
        // publish beta_511 (pre-rescale) + toteB
        if (ow0) wsb[514 + s0]     = b0;
        if (ow1) wsb[514 + s0 + 1] = b1;
        if (ow2) wsb[514 + s0 + 2] = b2;
        if (ow3) wsb[514 + s0 + 3] = b3;
        if (tid == 0) wsb[1027] = (double)tote;
    }
}

__global__ __launch_bounds__(64) void ctc_combine(
    const int* __restrict__ label_length,
    const double* __restrict__ ws,
    float* __restrict__ out)
{
    const int b = blockIdx.x;
    const int lane = (int)threadIdx.x;
    const int lab_len = label_length[b];
    const int S2 = 2 * lab_len + 1;
    const double* wf = ws + (size_t)b * WSSTRIDE;
    const double* wb = wf + 514;

    int eP = 0;                            // max biased-exponent sum of products
    for (int s = lane; s < S2; s += 64) {
        const int ea = (__double2hiint(wf[s]) >> 20) & 0x7ff;
        const int eb = (__double2hiint(wb[s]) >> 20) & 0x7ff;
        if (ea && eb) eP = max(eP, ea + eb);
    }
    #pragma unroll
    for (int m = 1; m < 64; m <<= 1) eP = max(eP, __shfl_xor(eP, m));
    const int sh = 2046 - eP;
    int k1 = sh / 2;
    int k2 = sh - k1;
    k1 = min(max(k1, -1022), 1023);
    k2 = min(max(k2, -1022), 1023);
    const double scA = __hiloint2double((1023 + k1) << 20, 0);
    const double scB = __hiloint2double((1023 + k2) << 20, 0);
    double dot = 0.0;
    for (int s = lane; s < S2; s += 64)
        dot += (wf[s] * scA) * (wb[s] * scB);
    #pragma unroll
    for (int m = 1; m < 64; m <<= 1) dot += __shfl_xor(dot, m);
    if (lane == 0) {
        const double lt = wf[513] + wb[513] - (double)k1 - (double)k2;
        out[b] = (float)(-(log(dot) + lt * 0.6931471805599453));
    }
}

extern "C" void kernel_launch(void* const* d_in, const int* in_sizes, int n_in,
                              void* d_out, int out_size, void* d_ws, size_t ws_size,
                              hipStream_t stream) {
    const int*   y_true       = (const int*)d_in[0];
    const float* y_pred       = (const float*)d_in[1];
    const int*   label_length = (const int*)d_in[3];
    float* out = (float*)d_out;
    double* ws = (double*)d_ws;

    ctc_fb_kernel<<<2 * Bc, NW * 64, 0, stream>>>(y_true, y_pred,
                                                  label_length, ws);
    ctc_combine<<<Bc, 64, 0, stream>>>(label_length, ws, out);
}